// Round 11
// baseline (253.678 us; speedup 1.0000x reference)
//
#include <hip/hip_runtime.h>

// HMM forward, log-semiring chunked scan. R11: R10 with ONE change —
// __launch_bounds__(256,6) -> (256,4). Bisection: R9 (cap 64) and R10
// (cap 85) both NaN'd; R8 (cap 128) passed. All other R10 deltas were
// audited clean. If this passes, the VGPR-cap/spill regime was the culprit.
// B=8, T=4096, S=64.  C=256 chunks of L=16 steps.
// Phase 1: reverse product G = F_t * G_old, reg-staged F, col-rescale
//   every 4 steps, separate orow. L=16.
// Reduce: R8's verified 8-wave kernel; level-0 folds 32 chunks/wave.

#define HMM_B 8
#define HMM_T 4096
#define HMM_S 64
#define HMM_C 256
#define HMM_L 16

typedef __attribute__((ext_vector_type(8))) short s16x8;
typedef __attribute__((ext_vector_type(4))) float f32x4;
typedef __attribute__((ext_vector_type(4))) unsigned int u32x4;
typedef unsigned long long u64t;

__device__ inline unsigned cvtpk(float lo, float hi) {
  unsigned r;
  asm("v_cvt_pk_bf16_f32 %0, %1, %2" : "=v"(r) : "v"(lo), "v"(hi));
  return r;
}
__device__ inline float bflo(unsigned w) { return __uint_as_float(w << 16); }
__device__ inline float bfhi(unsigned w) { return __uint_as_float(w & 0xffff0000u); }

// ---------------- Phase 1 (R8 structure, L=16, natural VGPR) ----------------

__global__ __launch_bounds__(256, 4)
void hmm_phase1(const float* __restrict__ lf, unsigned short* __restrict__ wsX,
                float* __restrict__ wsM) {
  // LDS: 16384 (gscr) + 1024 (cmax) + 9216 (orow) = 26624 B.
  __shared__ struct {
    unsigned short gscr[2][4096];   // G in B-frag-linear slots, dbuf
    float cmax[256];                // [j][w] per-wave colmax partials
    unsigned short orow[64 * 72];   // final G row-major, stride 72
  } sm;

  const int tid = threadIdx.x;
  const int w = tid >> 6, l = tid & 63;
  const int c4 = l & 15, q = l >> 4;
  const int wg = blockIdx.x;
  const int bb = wg >> 8, cc = wg & (HMM_C - 1);
  const size_t chunkbase = ((size_t)(bb * HMM_T + cc * HMM_L)) * 4096;
  // my A-operand source: rows 16w+c4, k-start 8q (+0/4, +32/36)
  const float* fb0 = lf + chunkbase + (size_t)(16 * w + c4) * 64 + 8 * q;

  // ---- init gscr[0] = Identity (B-frag-linear: slot(g,j), g=row-octet)
#pragma unroll
  for (int s = 0; s < 2; ++s) {
    int gg = w * 2 + s;   // 0..7
    int j = l;
    int slot = ((gg >> 2) * 4 + (j >> 4)) * 64 + (gg & 3) * 16 + (j & 15);
    unsigned short e8[8];
#pragma unroll
    for (int e = 0; e < 8; ++e)
      e8[e] = (unsigned short)((8 * gg + e == j) ? 0x3F80 : 0);
    *(u32x4*)&sm.gscr[0][slot * 8] = *(const u32x4*)e8;
  }
  float macc[4] = {0.f, 0.f, 0.f, 0.f};
  __syncthreads();

  f32x4 acc[4];

  auto ldf = [&](int t, float4& d0, float4& d1, float4& d2, float4& d3) {
    const float* p = fb0 + (size_t)t * 4096;
    d0 = *(const float4*)(p);
    d1 = *(const float4*)(p + 4);
    d2 = *(const float4*)(p + 32);
    d3 = *(const float4*)(p + 36);
  };

  auto step = [&](float4 f0, float4 f1, float4 f2, float4 f3, int pr, int t) {
    // A = exp(f rows), k ascending
    u32x4 ua, ub;
    ua.x = cvtpk(__expf(f0.x), __expf(f0.y));
    ua.y = cvtpk(__expf(f0.z), __expf(f0.w));
    ua.z = cvtpk(__expf(f1.x), __expf(f1.y));
    ua.w = cvtpk(__expf(f1.z), __expf(f1.w));
    ub.x = cvtpk(__expf(f2.x), __expf(f2.y));
    ub.y = cvtpk(__expf(f2.z), __expf(f2.w));
    ub.z = cvtpk(__expf(f3.x), __expf(f3.y));
    ub.w = cvtpk(__expf(f3.z), __expf(f3.w));
    s16x8 a0 = *(s16x8*)&ua, a1 = *(s16x8*)&ub;
#pragma unroll
    for (int n = 0; n < 4; ++n) {
      s16x8 b0 = *(const s16x8*)&sm.gscr[pr][(n * 64 + l) * 8];
      s16x8 b1 = *(const s16x8*)&sm.gscr[pr][((4 + n) * 64 + l) * 8];
      f32x4 c = {0.f, 0.f, 0.f, 0.f};
      c = __builtin_amdgcn_mfma_f32_16x16x32_bf16(a0, b0, c, 0, 0, 0);
      c = __builtin_amdgcn_mfma_f32_16x16x32_bf16(a1, b1, c, 0, 0, 0);
      acc[n] = c;
    }
    const bool rs = (t & 3) == 0;   // rescale every 4th step (incl. t=0)
    float inv[4] = {1.f, 1.f, 1.f, 1.f};
    if (rs) {
#pragma unroll
      for (int n = 0; n < 4; ++n) {
        float pmx = fmaxf(fmaxf(acc[n][0], acc[n][1]), fmaxf(acc[n][2], acc[n][3]));
        pmx = fmaxf(pmx, __shfl_xor(pmx, 16));
        pmx = fmaxf(pmx, __shfl_xor(pmx, 32));
        if (l < 16) sm.cmax[(16 * n + l) * 4 + w] = pmx;
      }
      __syncthreads();
#pragma unroll
      for (int n = 0; n < 4; ++n) {
        f32x4 cm = *(const f32x4*)&sm.cmax[(16 * n + c4) * 4];
        float m = fmaxf(fmaxf(cm[0], cm[1]), fmaxf(cm[2], cm[3]));
        m = fmaxf(m, 1e-30f);
        macc[n] += __log2f(m);
        inv[n] = __builtin_amdgcn_rcpf(m);
      }
    }
    if (t == 0) {
      // final: normalized acc -> orow (row-major), skip gscr store
#pragma unroll
      for (int n = 0; n < 4; ++n) {
        unsigned p01 = cvtpk(acc[n][0] * inv[n], acc[n][1] * inv[n]);
        unsigned p23 = cvtpk(acc[n][2] * inv[n], acc[n][3] * inv[n]);
        int base = 16 * n + c4, i0 = 16 * w + 4 * q;
        sm.orow[(i0 + 0) * 72 + base] = (unsigned short)(p01 & 0xffffu);
        sm.orow[(i0 + 1) * 72 + base] = (unsigned short)(p01 >> 16);
        sm.orow[(i0 + 2) * 72 + base] = (unsigned short)(p23 & 0xffffu);
        sm.orow[(i0 + 3) * 72 + base] = (unsigned short)(p23 >> 16);
      }
    } else {
      const int gg = 2 * w + (q >> 1);   // row-octet of rows 16w+4q..+3
#pragma unroll
      for (int n = 0; n < 4; ++n) {
        float s0, s1, s2, s3;
        if (rs) {
          s0 = acc[n][0] * inv[n]; s1 = acc[n][1] * inv[n];
          s2 = acc[n][2] * inv[n]; s3 = acc[n][3] * inv[n];
        } else {
          s0 = acc[n][0]; s1 = acc[n][1]; s2 = acc[n][2]; s3 = acc[n][3];
        }
        unsigned lo = cvtpk(s0, s1), hi = cvtpk(s2, s3);
        int slot = ((gg >> 2) * 4 + n) * 64 + (gg & 3) * 16 + c4;
        *(u64t*)((char*)sm.gscr[pr ^ 1] + slot * 16 + (q & 1) * 8) =
            (u64t)lo | ((u64t)hi << 32);
      }
    }
    __syncthreads();
  };

  float4 fA0, fA1, fA2, fA3, fB0, fB1, fB2, fB3;
  ldf(HMM_L - 1, fA0, fA1, fA2, fA3);
  for (int tt = 0; tt < HMM_L; tt += 2) {
    const int t0 = HMM_L - 1 - tt;
    ldf(t0 - 1, fB0, fB1, fB2, fB3);          // t0 >= 1 always here
    step(fA0, fA1, fA2, fA3, tt & 1, t0);
    if (t0 - 2 >= 0) ldf(t0 - 2, fA0, fA1, fA2, fA3);
    step(fB0, fB1, fB2, fB3, (tt + 1) & 1, t0 - 1);
  }

  // ---- write chunk results: wsX = row-major G (coalesced), wsM = col-logs
  {
    const size_t cb = ((size_t)(bb * HMM_C + cc)) * 4096;
    const int i = tid >> 2, c16 = (tid & 3) * 16;
    u32x4 v0 = *(const u32x4*)&sm.orow[i * 72 + c16];
    u32x4 v1 = *(const u32x4*)&sm.orow[i * 72 + c16 + 8];
    *(u32x4*)&wsX[cb + i * 64 + c16] = v0;
    *(u32x4*)&wsX[cb + i * 64 + c16 + 8] = v1;

    if (w == 0 && l < 16) {
      const float ln2 = 0.6931471805599453f;
#pragma unroll
      for (int n = 0; n < 4; ++n)
        wsM[(size_t)(bb * HMM_C + cc) * 64 + 16 * n + l] = macc[n] * ln2;
    }
  }
}

// ---------------- Reduce (R8's verified folds; 32 chunks/wave level 0) -----
// Folds T_s = C_{255-s}^T left-to-right; T's B-frag = wsX row-major data.
// Fold: prod' = prod . diag(exp(m_c - nu)) . T_c, row-normalized;
//       pmAcc[i] += nu + log(rowmax_i).

#define PMS 72   // pmat row stride (ushorts); 144 B, 16B-aligned rows

__global__ __launch_bounds__(512)
void hmm_reduce(const unsigned short* __restrict__ Xt, const float* __restrict__ M,
                const float* __restrict__ linit, float* __restrict__ out) {
  __shared__ unsigned short pmat[8][PMS * 64];  // partials + roundtrip scratch
  __shared__ float pm[8][64];
  __shared__ float sS[8][64];
  __shared__ float sLin[64];

  const int tid = threadIdx.x;
  const int v = tid >> 6, l = tid & 63, c4 = l & 15, q = l >> 4;
  const int b = blockIdx.x;

  if (tid < 64) sLin[tid] = linit[b * 64 + tid];
  pm[v][l] = 0.0f;

  // identity A fragments
  s16x8 afr[4][2];
#pragma unroll
  for (int m = 0; m < 4; ++m)
#pragma unroll
    for (int h = 0; h < 2; ++h)
#pragma unroll
      for (int e = 0; e < 8; ++e)
        afr[m][h][e] = (short)((32 * h + 8 * q + e == 16 * m + c4) ? 0x3F80 : 0);

  f32x4 acc[4][4];
  float rmax[4][4];

  auto fold = [&](u32x4 (&bcur)[2][4], float mcur, float* pmAcc, float* sSv) {
    float nu = mcur;
    nu = fmaxf(nu, __shfl_xor(nu, 1));  nu = fmaxf(nu, __shfl_xor(nu, 2));
    nu = fmaxf(nu, __shfl_xor(nu, 4));  nu = fmaxf(nu, __shfl_xor(nu, 8));
    nu = fmaxf(nu, __shfl_xor(nu, 16)); nu = fmaxf(nu, __shfl_xor(nu, 32));
    sSv[l] = __expf(mcur - nu);
    s16x8 bfr[2][4];
#pragma unroll
    for (int h = 0; h < 2; ++h) {
      f32x4 s0 = *(const f32x4*)&sSv[h * 32 + q * 8];
      f32x4 s1 = *(const f32x4*)&sSv[h * 32 + q * 8 + 4];
#pragma unroll
      for (int n = 0; n < 4; ++n) {
        u32x4 raw = bcur[h][n];
        unsigned p0 = cvtpk(bflo(raw.x) * s0[0], bfhi(raw.x) * s0[1]);
        unsigned p1 = cvtpk(bflo(raw.y) * s0[2], bfhi(raw.y) * s0[3]);
        unsigned p2 = cvtpk(bflo(raw.z) * s1[0], bfhi(raw.z) * s1[1]);
        unsigned p3 = cvtpk(bflo(raw.w) * s1[2], bfhi(raw.w) * s1[3]);
        u32x4 o; o.x = p0; o.y = p1; o.z = p2; o.w = p3;
        bfr[h][n] = *(s16x8*)&o;
      }
    }
#pragma unroll
    for (int m = 0; m < 4; ++m)
#pragma unroll
      for (int n = 0; n < 4; ++n) {
        f32x4 c = {0.f, 0.f, 0.f, 0.f};
        c = __builtin_amdgcn_mfma_f32_16x16x32_bf16(afr[m][0], bfr[0][n], c, 0, 0, 0);
        c = __builtin_amdgcn_mfma_f32_16x16x32_bf16(afr[m][1], bfr[1][n], c, 0, 0, 0);
        acc[m][n] = c;
      }
#pragma unroll
    for (int m = 0; m < 4; ++m)
#pragma unroll
      for (int r = 0; r < 4; ++r) {
        float x = fmaxf(fmaxf(acc[m][0][r], acc[m][1][r]),
                        fmaxf(acc[m][2][r], acc[m][3][r]));
        x = fmaxf(x, __shfl_xor(x, 1));
        x = fmaxf(x, __shfl_xor(x, 2));
        x = fmaxf(x, __shfl_xor(x, 4));
        x = fmaxf(x, __shfl_xor(x, 8));
        rmax[m][r] = fmaxf(x, 1e-30f);
      }
    if (c4 == 0) {
#pragma unroll
      for (int m = 0; m < 4; ++m)
#pragma unroll
        for (int r = 0; r < 4; ++r)
          pmAcc[16 * m + 4 * q + r] += nu + __logf(rmax[m][r]);
    }
  };

  auto roundtrip = [&](unsigned short* ps) {
#pragma unroll
    for (int m = 0; m < 4; ++m) {
      float i0 = __builtin_amdgcn_rcpf(rmax[m][0]);
      float i1 = __builtin_amdgcn_rcpf(rmax[m][1]);
      float i2 = __builtin_amdgcn_rcpf(rmax[m][2]);
      float i3 = __builtin_amdgcn_rcpf(rmax[m][3]);
#pragma unroll
      for (int n = 0; n < 4; ++n) {
        unsigned p01 = cvtpk(acc[m][n][0] * i0, acc[m][n][1] * i1);
        unsigned p23 = cvtpk(acc[m][n][2] * i2, acc[m][n][3] * i3);
        ps[(16 * m + 4 * q + 0) * PMS + 16 * n + c4] = (unsigned short)(p01 & 0xffffu);
        ps[(16 * m + 4 * q + 1) * PMS + 16 * n + c4] = (unsigned short)(p01 >> 16);
        ps[(16 * m + 4 * q + 2) * PMS + 16 * n + c4] = (unsigned short)(p23 & 0xffffu);
        ps[(16 * m + 4 * q + 3) * PMS + 16 * n + c4] = (unsigned short)(p23 >> 16);
      }
    }
#pragma unroll
    for (int m = 0; m < 4; ++m)
#pragma unroll
      for (int h = 0; h < 2; ++h)
        afr[m][h] = *(const s16x8*)&ps[(16 * m + c4) * PMS + 32 * h + 8 * q];
  };

  auto storeEt = [&](unsigned short* pd) {
#pragma unroll
    for (int m = 0; m < 4; ++m) {
      float i0 = __builtin_amdgcn_rcpf(rmax[m][0]);
      float i1 = __builtin_amdgcn_rcpf(rmax[m][1]);
      float i2 = __builtin_amdgcn_rcpf(rmax[m][2]);
      float i3 = __builtin_amdgcn_rcpf(rmax[m][3]);
#pragma unroll
      for (int n = 0; n < 4; ++n) {
        unsigned p01 = cvtpk(acc[m][n][0] * i0, acc[m][n][1] * i1);
        unsigned p23 = cvtpk(acc[m][n][2] * i2, acc[m][n][3] * i3);
        u64t packed = (u64t)p01 | ((u64t)p23 << 32);
        *(u64t*)&pd[(16 * n + c4) * PMS + 16 * m + 4 * q] = packed;
      }
    }
  };

  // ---- level 0: wave v folds 32 transposed chunks in reverse order
  //      (global chunk index 255-32v down to 224-32v)
  {
    const int cidx0 = b * HMM_C + (HMM_C - 1) - 32 * v;
    u32x4 braw[2][4];
    float mv;
#pragma unroll
    for (int h = 0; h < 2; ++h)
#pragma unroll
      for (int n = 0; n < 4; ++n)
        braw[h][n] = *(const u32x4*)&Xt[(size_t)cidx0 * 4096 +
                                        (16 * n + c4) * 64 + 32 * h + 8 * q];
    mv = M[(size_t)cidx0 * 64 + l];

    for (int c = 0; c < 32; ++c) {
      u32x4 bcur[2][4];
#pragma unroll
      for (int h = 0; h < 2; ++h)
#pragma unroll
        for (int n = 0; n < 4; ++n) bcur[h][n] = braw[h][n];
      float mcur = mv;
      if (c < 31) {
        const size_t cb = (size_t)(cidx0 - (c + 1)) * 4096;
#pragma unroll
        for (int h = 0; h < 2; ++h)
#pragma unroll
          for (int n = 0; n < 4; ++n)
            braw[h][n] = *(const u32x4*)&Xt[cb + (16 * n + c4) * 64 + 32 * h + 8 * q];
        mv = M[(size_t)(cidx0 - (c + 1)) * 64 + l];
      }
      fold(bcur, mcur, pm[v], sS[v]);
      if (c < 31) roundtrip(pmat[v]);
      else        storeEt(pmat[v]);
    }
  }
  __syncthreads();

  // ---- level 1: waves 0,1 fold partial slots [4v, 4v+4)
  if (v < 2) {
    const int sb = 4 * v;
#pragma unroll
    for (int m = 0; m < 4; ++m)
#pragma unroll
      for (int h = 0; h < 2; ++h)
#pragma unroll
        for (int e = 0; e < 8; ++e)
          afr[m][h][e] = (short)pmat[sb][(32 * h + 8 * q + e) * PMS + 16 * m + c4];
    for (int c = 1; c < 4; ++c) {
      u32x4 bcur[2][4];
#pragma unroll
      for (int h = 0; h < 2; ++h)
#pragma unroll
        for (int n = 0; n < 4; ++n)
          bcur[h][n] = *(const u32x4*)&pmat[sb + c][(16 * n + c4) * PMS + 32 * h + 8 * q];
      float mcur = pm[sb + c][l];
      fold(bcur, mcur, pm[sb], sS[v]);
      if (v == 0)      roundtrip(pmat[0]);
      else if (c < 3)  roundtrip(pmat[4]);
      else             storeEt(pmat[4]);
    }
  }
  __syncthreads();

  // ---- level 2 + final: wave 0 folds pmat[4], then logsumexp matvec
  if (v == 0) {
    u32x4 bcur[2][4];
#pragma unroll
    for (int h = 0; h < 2; ++h)
#pragma unroll
      for (int n = 0; n < 4; ++n)
        bcur[h][n] = *(const u32x4*)&pmat[4][(16 * n + c4) * PMS + 32 * h + 8 * q];
    float mcur = pm[4][l];

    float nu = mcur;
    nu = fmaxf(nu, __shfl_xor(nu, 1));  nu = fmaxf(nu, __shfl_xor(nu, 2));
    nu = fmaxf(nu, __shfl_xor(nu, 4));  nu = fmaxf(nu, __shfl_xor(nu, 8));
    nu = fmaxf(nu, __shfl_xor(nu, 16)); nu = fmaxf(nu, __shfl_xor(nu, 32));
    sS[0][l] = __expf(mcur - nu);
    s16x8 bfr[2][4];
#pragma unroll
    for (int h = 0; h < 2; ++h) {
      f32x4 s0 = *(const f32x4*)&sS[0][h * 32 + q * 8];
      f32x4 s1 = *(const f32x4*)&sS[0][h * 32 + q * 8 + 4];
#pragma unroll
      for (int n = 0; n < 4; ++n) {
        u32x4 raw = bcur[h][n];
        unsigned p0 = cvtpk(bflo(raw.x) * s0[0], bfhi(raw.x) * s0[1]);
        unsigned p1 = cvtpk(bflo(raw.y) * s0[2], bfhi(raw.y) * s0[3]);
        unsigned p2 = cvtpk(bflo(raw.z) * s1[0], bfhi(raw.z) * s1[1]);
        unsigned p3 = cvtpk(bflo(raw.w) * s1[2], bfhi(raw.w) * s1[3]);
        u32x4 o; o.x = p0; o.y = p1; o.z = p2; o.w = p3;
        bfr[h][n] = *(s16x8*)&o;
      }
    }
#pragma unroll
    for (int m = 0; m < 4; ++m)
#pragma unroll
      for (int n = 0; n < 4; ++n) {
        f32x4 c = {0.f, 0.f, 0.f, 0.f};
        c = __builtin_amdgcn_mfma_f32_16x16x32_bf16(afr[m][0], bfr[0][n], c, 0, 0, 0);
        c = __builtin_amdgcn_mfma_f32_16x16x32_bf16(afr[m][1], bfr[1][n], c, 0, 0, 0);
        acc[m][n] = c;
      }

    // acc = Mt (unnorm.); true M^T = diag(e^pm0) . acc . e^nu
    float tl = sLin[l];
    float mL = tl;
    mL = fmaxf(mL, __shfl_xor(mL, 1));  mL = fmaxf(mL, __shfl_xor(mL, 2));
    mL = fmaxf(mL, __shfl_xor(mL, 4));  mL = fmaxf(mL, __shfl_xor(mL, 8));
    mL = fmaxf(mL, __shfl_xor(mL, 16)); mL = fmaxf(mL, __shfl_xor(mL, 32));
    float wn[4];
#pragma unroll
    for (int n = 0; n < 4; ++n) wn[n] = __expf(sLin[16 * n + c4] - mL);

    float pj = pm[0][l];
    float kap = pj;
    kap = fmaxf(kap, __shfl_xor(kap, 1));  kap = fmaxf(kap, __shfl_xor(kap, 2));
    kap = fmaxf(kap, __shfl_xor(kap, 4));  kap = fmaxf(kap, __shfl_xor(kap, 8));
    kap = fmaxf(kap, __shfl_xor(kap, 16)); kap = fmaxf(kap, __shfl_xor(kap, 32));

    float tot = 0.f;
#pragma unroll
    for (int m = 0; m < 4; ++m)
#pragma unroll
      for (int r = 0; r < 4; ++r) {
        float p = acc[m][0][r] * wn[0] + acc[m][1][r] * wn[1] +
                  acc[m][2][r] * wn[2] + acc[m][3][r] * wn[3];
        p += __shfl_xor(p, 1); p += __shfl_xor(p, 2);
        p += __shfl_xor(p, 4); p += __shfl_xor(p, 8);
        if (c4 == 0) {
          int j = 16 * m + 4 * q + r;
          tot += __expf(pm[0][j] - kap) * p;
        }
      }
    tot += __shfl_xor(tot, 16);
    tot += __shfl_xor(tot, 32);
    if (l == 0) out[b] = nu + mL + kap + __logf(tot);
  }
}

extern "C" void kernel_launch(void* const* d_in, const int* in_sizes, int n_in,
                              void* d_out, int out_size, void* d_ws, size_t ws_size,
                              hipStream_t stream) {
  (void)in_sizes; (void)n_in; (void)out_size; (void)ws_size;
  const float* lf    = (const float*)d_in[0];  // [B,T,S,S] fp32
  const float* linit = (const float*)d_in[1];  // [B,S] fp32
  float* out = (float*)d_out;                  // [B] fp32

  unsigned short* wsX = (unsigned short*)d_ws;                  // 16 MB bf16
  float*          wsM = (float*)(wsX + (size_t)HMM_B * HMM_C * 4096);  // 512 KB

  hmm_phase1<<<dim3(HMM_B * HMM_C), dim3(256), 0, stream>>>(lf, wsX, wsM);
  hmm_reduce<<<dim3(HMM_B), dim3(512), 0, stream>>>(wsX, wsM, linit, out);
}

// Round 12
// 185.768 us; speedup vs baseline: 1.3656x; 1.3656x over previous
//
#include <hip/hip_runtime.h>

// HMM forward, log-semiring chunked scan. R12: R8 verbatim + ONE change —
// phase1 column-rescale interval 4 -> 8 steps ((t&7)==0). Growth bound
// (64*e^4.5)^8 ~ 6e30 < 3.4e38 (bf16 = fp32 exponent range): safe.
// B=8, T=4096, S=64.  C=128 chunks of L=32 steps.
// Phase 1 (1024 WGs, 256 thr, 4 WGs/CU): reverse product G = F_t * G_old,
//   t = 31..0. F rows = MFMA A-operand staged global->registers (depth-1
//   ping-pong). State G in 8KB B-frag-linear LDS, double-buffered.
//   Output: wsX[chunk] = row-major G (bf16); wsM[chunk] = col-logs (f32).
// Reduce (8 WGs, 512 thr): R8's verified fold kernel (16 chunks/wave level 0,
//   transposed chunks in reverse order, 2-level tree + logsumexp epilogue).

#define HMM_B 8
#define HMM_T 4096
#define HMM_S 64
#define HMM_C 128
#define HMM_L 32

typedef __attribute__((ext_vector_type(8))) short s16x8;
typedef __attribute__((ext_vector_type(4))) float f32x4;
typedef __attribute__((ext_vector_type(4))) unsigned int u32x4;
typedef unsigned long long u64t;

__device__ inline unsigned cvtpk(float lo, float hi) {
  unsigned r;
  asm("v_cvt_pk_bf16_f32 %0, %1, %2" : "=v"(r) : "v"(lo), "v"(hi));
  return r;
}
__device__ inline float bflo(unsigned w) { return __uint_as_float(w << 16); }
__device__ inline float bfhi(unsigned w) { return __uint_as_float(w & 0xffff0000u); }

// ---------------- Phase 1 ----------------

__global__ __launch_bounds__(256, 4)
void hmm_phase1(const float* __restrict__ lf, unsigned short* __restrict__ wsX,
                float* __restrict__ wsM) {
  // LDS: 16384 (gscr) + 1024 (cmax) + 9216 (orow) = 26624 B.
  __shared__ struct {
    unsigned short gscr[2][4096];   // G in B-frag-linear slots, dbuf
    float cmax[256];                // [j][w] per-wave colmax partials
    unsigned short orow[64 * 72];   // final G row-major, stride 72
  } sm;

  const int tid = threadIdx.x;
  const int w = tid >> 6, l = tid & 63;
  const int c4 = l & 15, q = l >> 4;
  const int wg = blockIdx.x;
  const int bb = wg >> 7, cc = wg & (HMM_C - 1);
  const size_t chunkbase = ((size_t)(bb * HMM_T + cc * HMM_L)) * 4096;
  // my A-operand source: rows 16w+c4, k-start 8q (+0/4, +32/36)
  const float* fb0 = lf + chunkbase + (size_t)(16 * w + c4) * 64 + 8 * q;

  // ---- init gscr[0] = Identity (B-frag-linear: slot(g,j), g=row-octet)
#pragma unroll
  for (int s = 0; s < 2; ++s) {
    int gg = w * 2 + s;   // 0..7
    int j = l;
    int slot = ((gg >> 2) * 4 + (j >> 4)) * 64 + (gg & 3) * 16 + (j & 15);
    unsigned short e8[8];
#pragma unroll
    for (int e = 0; e < 8; ++e)
      e8[e] = (unsigned short)((8 * gg + e == j) ? 0x3F80 : 0);
    *(u32x4*)&sm.gscr[0][slot * 8] = *(const u32x4*)e8;
  }
  float macc[4] = {0.f, 0.f, 0.f, 0.f};
  __syncthreads();

  f32x4 acc[4];

  auto ldf = [&](int t, float4& d0, float4& d1, float4& d2, float4& d3) {
    const float* p = fb0 + (size_t)t * 4096;
    d0 = *(const float4*)(p);
    d1 = *(const float4*)(p + 4);
    d2 = *(const float4*)(p + 32);
    d3 = *(const float4*)(p + 36);
  };

  auto step = [&](float4 f0, float4 f1, float4 f2, float4 f3, int pr, int t) {
    // A = exp(f rows), k ascending
    u32x4 ua, ub;
    ua.x = cvtpk(__expf(f0.x), __expf(f0.y));
    ua.y = cvtpk(__expf(f0.z), __expf(f0.w));
    ua.z = cvtpk(__expf(f1.x), __expf(f1.y));
    ua.w = cvtpk(__expf(f1.z), __expf(f1.w));
    ub.x = cvtpk(__expf(f2.x), __expf(f2.y));
    ub.y = cvtpk(__expf(f2.z), __expf(f2.w));
    ub.z = cvtpk(__expf(f3.x), __expf(f3.y));
    ub.w = cvtpk(__expf(f3.z), __expf(f3.w));
    s16x8 a0 = *(s16x8*)&ua, a1 = *(s16x8*)&ub;
#pragma unroll
    for (int n = 0; n < 4; ++n) {
      s16x8 b0 = *(const s16x8*)&sm.gscr[pr][(n * 64 + l) * 8];
      s16x8 b1 = *(const s16x8*)&sm.gscr[pr][((4 + n) * 64 + l) * 8];
      f32x4 c = {0.f, 0.f, 0.f, 0.f};
      c = __builtin_amdgcn_mfma_f32_16x16x32_bf16(a0, b0, c, 0, 0, 0);
      c = __builtin_amdgcn_mfma_f32_16x16x32_bf16(a1, b1, c, 0, 0, 0);
      acc[n] = c;
    }
    const bool rs = (t & 7) == 0;   // rescale every 8th step (incl. t=0)
    float inv[4] = {1.f, 1.f, 1.f, 1.f};
    if (rs) {
#pragma unroll
      for (int n = 0; n < 4; ++n) {
        float pmx = fmaxf(fmaxf(acc[n][0], acc[n][1]), fmaxf(acc[n][2], acc[n][3]));
        pmx = fmaxf(pmx, __shfl_xor(pmx, 16));
        pmx = fmaxf(pmx, __shfl_xor(pmx, 32));
        if (l < 16) sm.cmax[(16 * n + l) * 4 + w] = pmx;
      }
      __syncthreads();
#pragma unroll
      for (int n = 0; n < 4; ++n) {
        f32x4 cm = *(const f32x4*)&sm.cmax[(16 * n + c4) * 4];
        float m = fmaxf(fmaxf(cm[0], cm[1]), fmaxf(cm[2], cm[3]));
        m = fmaxf(m, 1e-30f);
        macc[n] += __log2f(m);
        inv[n] = __builtin_amdgcn_rcpf(m);
      }
    }
    if (t == 0) {
      // final: normalized acc -> orow (row-major), skip gscr store
#pragma unroll
      for (int n = 0; n < 4; ++n) {
        unsigned p01 = cvtpk(acc[n][0] * inv[n], acc[n][1] * inv[n]);
        unsigned p23 = cvtpk(acc[n][2] * inv[n], acc[n][3] * inv[n]);
        int base = 16 * n + c4, i0 = 16 * w + 4 * q;
        sm.orow[(i0 + 0) * 72 + base] = (unsigned short)(p01 & 0xffffu);
        sm.orow[(i0 + 1) * 72 + base] = (unsigned short)(p01 >> 16);
        sm.orow[(i0 + 2) * 72 + base] = (unsigned short)(p23 & 0xffffu);
        sm.orow[(i0 + 3) * 72 + base] = (unsigned short)(p23 >> 16);
      }
    } else {
      const int gg = 2 * w + (q >> 1);   // row-octet of rows 16w+4q..+3
#pragma unroll
      for (int n = 0; n < 4; ++n) {
        float s0, s1, s2, s3;
        if (rs) {
          s0 = acc[n][0] * inv[n]; s1 = acc[n][1] * inv[n];
          s2 = acc[n][2] * inv[n]; s3 = acc[n][3] * inv[n];
        } else {
          s0 = acc[n][0]; s1 = acc[n][1]; s2 = acc[n][2]; s3 = acc[n][3];
        }
        unsigned lo = cvtpk(s0, s1), hi = cvtpk(s2, s3);
        int slot = ((gg >> 2) * 4 + n) * 64 + (gg & 3) * 16 + c4;
        *(u64t*)((char*)sm.gscr[pr ^ 1] + slot * 16 + (q & 1) * 8) =
            (u64t)lo | ((u64t)hi << 32);
      }
    }
    __syncthreads();
  };

  float4 fA0, fA1, fA2, fA3, fB0, fB1, fB2, fB3;
  ldf(HMM_L - 1, fA0, fA1, fA2, fA3);
  for (int tt = 0; tt < HMM_L; tt += 2) {
    const int t0 = HMM_L - 1 - tt;
    ldf(t0 - 1, fB0, fB1, fB2, fB3);          // t0 >= 1 always here
    step(fA0, fA1, fA2, fA3, tt & 1, t0);
    if (t0 - 2 >= 0) ldf(t0 - 2, fA0, fA1, fA2, fA3);
    step(fB0, fB1, fB2, fB3, (tt + 1) & 1, t0 - 1);
  }

  // ---- write chunk results: wsX = row-major G (coalesced), wsM = col-logs
  {
    const size_t cb = ((size_t)(bb * HMM_C + cc)) * 4096;
    const int i = tid >> 2, c16 = (tid & 3) * 16;
    u32x4 v0 = *(const u32x4*)&sm.orow[i * 72 + c16];
    u32x4 v1 = *(const u32x4*)&sm.orow[i * 72 + c16 + 8];
    *(u32x4*)&wsX[cb + i * 64 + c16] = v0;
    *(u32x4*)&wsX[cb + i * 64 + c16 + 8] = v1;

    if (w == 0 && l < 16) {
      const float ln2 = 0.6931471805599453f;
#pragma unroll
      for (int n = 0; n < 4; ++n)
        wsM[(size_t)(bb * HMM_C + cc) * 64 + 16 * n + l] = macc[n] * ln2;
    }
  }
}

// ---------------- Reduce (R8's verified folds) ----------------
// Folds T_s = C_{127-s}^T left-to-right; T's B-frag = wsX row-major data.
// Fold: prod' = prod . diag(exp(m_c - nu)) . T_c, row-normalized;
//       pmAcc[i] += nu + log(rowmax_i).

#define PMS 72   // pmat row stride (ushorts); 144 B, 16B-aligned rows

__global__ __launch_bounds__(512)
void hmm_reduce(const unsigned short* __restrict__ Xt, const float* __restrict__ M,
                const float* __restrict__ linit, float* __restrict__ out) {
  __shared__ unsigned short pmat[8][PMS * 64];  // partials + roundtrip scratch
  __shared__ float pm[8][64];
  __shared__ float sS[8][64];
  __shared__ float sLin[64];

  const int tid = threadIdx.x;
  const int v = tid >> 6, l = tid & 63, c4 = l & 15, q = l >> 4;
  const int b = blockIdx.x;

  if (tid < 64) sLin[tid] = linit[b * 64 + tid];
  pm[v][l] = 0.0f;

  // identity A fragments
  s16x8 afr[4][2];
#pragma unroll
  for (int m = 0; m < 4; ++m)
#pragma unroll
    for (int h = 0; h < 2; ++h)
#pragma unroll
      for (int e = 0; e < 8; ++e)
        afr[m][h][e] = (short)((32 * h + 8 * q + e == 16 * m + c4) ? 0x3F80 : 0);

  f32x4 acc[4][4];
  float rmax[4][4];

  auto fold = [&](u32x4 (&bcur)[2][4], float mcur, float* pmAcc, float* sSv) {
    float nu = mcur;
    nu = fmaxf(nu, __shfl_xor(nu, 1));  nu = fmaxf(nu, __shfl_xor(nu, 2));
    nu = fmaxf(nu, __shfl_xor(nu, 4));  nu = fmaxf(nu, __shfl_xor(nu, 8));
    nu = fmaxf(nu, __shfl_xor(nu, 16)); nu = fmaxf(nu, __shfl_xor(nu, 32));
    sSv[l] = __expf(mcur - nu);
    s16x8 bfr[2][4];
#pragma unroll
    for (int h = 0; h < 2; ++h) {
      f32x4 s0 = *(const f32x4*)&sSv[h * 32 + q * 8];
      f32x4 s1 = *(const f32x4*)&sSv[h * 32 + q * 8 + 4];
#pragma unroll
      for (int n = 0; n < 4; ++n) {
        u32x4 raw = bcur[h][n];
        unsigned p0 = cvtpk(bflo(raw.x) * s0[0], bfhi(raw.x) * s0[1]);
        unsigned p1 = cvtpk(bflo(raw.y) * s0[2], bfhi(raw.y) * s0[3]);
        unsigned p2 = cvtpk(bflo(raw.z) * s1[0], bfhi(raw.z) * s1[1]);
        unsigned p3 = cvtpk(bflo(raw.w) * s1[2], bfhi(raw.w) * s1[3]);
        u32x4 o; o.x = p0; o.y = p1; o.z = p2; o.w = p3;
        bfr[h][n] = *(s16x8*)&o;
      }
    }
#pragma unroll
    for (int m = 0; m < 4; ++m)
#pragma unroll
      for (int n = 0; n < 4; ++n) {
        f32x4 c = {0.f, 0.f, 0.f, 0.f};
        c = __builtin_amdgcn_mfma_f32_16x16x32_bf16(afr[m][0], bfr[0][n], c, 0, 0, 0);
        c = __builtin_amdgcn_mfma_f32_16x16x32_bf16(afr[m][1], bfr[1][n], c, 0, 0, 0);
        acc[m][n] = c;
      }
#pragma unroll
    for (int m = 0; m < 4; ++m)
#pragma unroll
      for (int r = 0; r < 4; ++r) {
        float x = fmaxf(fmaxf(acc[m][0][r], acc[m][1][r]),
                        fmaxf(acc[m][2][r], acc[m][3][r]));
        x = fmaxf(x, __shfl_xor(x, 1));
        x = fmaxf(x, __shfl_xor(x, 2));
        x = fmaxf(x, __shfl_xor(x, 4));
        x = fmaxf(x, __shfl_xor(x, 8));
        rmax[m][r] = fmaxf(x, 1e-30f);
      }
    if (c4 == 0) {
#pragma unroll
      for (int m = 0; m < 4; ++m)
#pragma unroll
        for (int r = 0; r < 4; ++r)
          pmAcc[16 * m + 4 * q + r] += nu + __logf(rmax[m][r]);
    }
  };

  auto roundtrip = [&](unsigned short* ps) {
#pragma unroll
    for (int m = 0; m < 4; ++m) {
      float i0 = __builtin_amdgcn_rcpf(rmax[m][0]);
      float i1 = __builtin_amdgcn_rcpf(rmax[m][1]);
      float i2 = __builtin_amdgcn_rcpf(rmax[m][2]);
      float i3 = __builtin_amdgcn_rcpf(rmax[m][3]);
#pragma unroll
      for (int n = 0; n < 4; ++n) {
        unsigned p01 = cvtpk(acc[m][n][0] * i0, acc[m][n][1] * i1);
        unsigned p23 = cvtpk(acc[m][n][2] * i2, acc[m][n][3] * i3);
        ps[(16 * m + 4 * q + 0) * PMS + 16 * n + c4] = (unsigned short)(p01 & 0xffffu);
        ps[(16 * m + 4 * q + 1) * PMS + 16 * n + c4] = (unsigned short)(p01 >> 16);
        ps[(16 * m + 4 * q + 2) * PMS + 16 * n + c4] = (unsigned short)(p23 & 0xffffu);
        ps[(16 * m + 4 * q + 3) * PMS + 16 * n + c4] = (unsigned short)(p23 >> 16);
      }
    }
#pragma unroll
    for (int m = 0; m < 4; ++m)
#pragma unroll
      for (int h = 0; h < 2; ++h)
        afr[m][h] = *(const s16x8*)&ps[(16 * m + c4) * PMS + 32 * h + 8 * q];
  };

  auto storeEt = [&](unsigned short* pd) {
#pragma unroll
    for (int m = 0; m < 4; ++m) {
      float i0 = __builtin_amdgcn_rcpf(rmax[m][0]);
      float i1 = __builtin_amdgcn_rcpf(rmax[m][1]);
      float i2 = __builtin_amdgcn_rcpf(rmax[m][2]);
      float i3 = __builtin_amdgcn_rcpf(rmax[m][3]);
#pragma unroll
      for (int n = 0; n < 4; ++n) {
        unsigned p01 = cvtpk(acc[m][n][0] * i0, acc[m][n][1] * i1);
        unsigned p23 = cvtpk(acc[m][n][2] * i2, acc[m][n][3] * i3);
        u64t packed = (u64t)p01 | ((u64t)p23 << 32);
        *(u64t*)&pd[(16 * n + c4) * PMS + 16 * m + 4 * q] = packed;
      }
    }
  };

  // ---- level 0: wave v folds 16 transposed chunks in reverse order
  //      (global chunk index 127-16v down to 112-16v)
  {
    const int cidx0 = b * HMM_C + (HMM_C - 1) - 16 * v;
    u32x4 braw[2][4];
    float mv;
#pragma unroll
    for (int h = 0; h < 2; ++h)
#pragma unroll
      for (int n = 0; n < 4; ++n)
        braw[h][n] = *(const u32x4*)&Xt[(size_t)cidx0 * 4096 +
                                        (16 * n + c4) * 64 + 32 * h + 8 * q];
    mv = M[(size_t)cidx0 * 64 + l];

    for (int c = 0; c < 16; ++c) {
      u32x4 bcur[2][4];
#pragma unroll
      for (int h = 0; h < 2; ++h)
#pragma unroll
        for (int n = 0; n < 4; ++n) bcur[h][n] = braw[h][n];
      float mcur = mv;
      if (c < 15) {
        const size_t cb = (size_t)(cidx0 - (c + 1)) * 4096;
#pragma unroll
        for (int h = 0; h < 2; ++h)
#pragma unroll
          for (int n = 0; n < 4; ++n)
            braw[h][n] = *(const u32x4*)&Xt[cb + (16 * n + c4) * 64 + 32 * h + 8 * q];
        mv = M[(size_t)(cidx0 - (c + 1)) * 64 + l];
      }
      fold(bcur, mcur, pm[v], sS[v]);
      if (c < 15) roundtrip(pmat[v]);
      else        storeEt(pmat[v]);
    }
  }
  __syncthreads();

  // ---- level 1: waves 0,1 fold partial slots [4v, 4v+4)
  if (v < 2) {
    const int sb = 4 * v;
#pragma unroll
    for (int m = 0; m < 4; ++m)
#pragma unroll
      for (int h = 0; h < 2; ++h)
#pragma unroll
        for (int e = 0; e < 8; ++e)
          afr[m][h][e] = (short)pmat[sb][(32 * h + 8 * q + e) * PMS + 16 * m + c4];
    for (int c = 1; c < 4; ++c) {
      u32x4 bcur[2][4];
#pragma unroll
      for (int h = 0; h < 2; ++h)
#pragma unroll
        for (int n = 0; n < 4; ++n)
          bcur[h][n] = *(const u32x4*)&pmat[sb + c][(16 * n + c4) * PMS + 32 * h + 8 * q];
      float mcur = pm[sb + c][l];
      fold(bcur, mcur, pm[sb], sS[v]);
      if (v == 0)      roundtrip(pmat[0]);
      else if (c < 3)  roundtrip(pmat[4]);
      else             storeEt(pmat[4]);
    }
  }
  __syncthreads();

  // ---- level 2 + final: wave 0 folds pmat[4], then logsumexp matvec
  if (v == 0) {
    u32x4 bcur[2][4];
#pragma unroll
    for (int h = 0; h < 2; ++h)
#pragma unroll
      for (int n = 0; n < 4; ++n)
        bcur[h][n] = *(const u32x4*)&pmat[4][(16 * n + c4) * PMS + 32 * h + 8 * q];
    float mcur = pm[4][l];

    float nu = mcur;
    nu = fmaxf(nu, __shfl_xor(nu, 1));  nu = fmaxf(nu, __shfl_xor(nu, 2));
    nu = fmaxf(nu, __shfl_xor(nu, 4));  nu = fmaxf(nu, __shfl_xor(nu, 8));
    nu = fmaxf(nu, __shfl_xor(nu, 16)); nu = fmaxf(nu, __shfl_xor(nu, 32));
    sS[0][l] = __expf(mcur - nu);
    s16x8 bfr[2][4];
#pragma unroll
    for (int h = 0; h < 2; ++h) {
      f32x4 s0 = *(const f32x4*)&sS[0][h * 32 + q * 8];
      f32x4 s1 = *(const f32x4*)&sS[0][h * 32 + q * 8 + 4];
#pragma unroll
      for (int n = 0; n < 4; ++n) {
        u32x4 raw = bcur[h][n];
        unsigned p0 = cvtpk(bflo(raw.x) * s0[0], bfhi(raw.x) * s0[1]);
        unsigned p1 = cvtpk(bflo(raw.y) * s0[2], bfhi(raw.y) * s0[3]);
        unsigned p2 = cvtpk(bflo(raw.z) * s1[0], bfhi(raw.z) * s1[1]);
        unsigned p3 = cvtpk(bflo(raw.w) * s1[2], bfhi(raw.w) * s1[3]);
        u32x4 o; o.x = p0; o.y = p1; o.z = p2; o.w = p3;
        bfr[h][n] = *(s16x8*)&o;
      }
    }
#pragma unroll
    for (int m = 0; m < 4; ++m)
#pragma unroll
      for (int n = 0; n < 4; ++n) {
        f32x4 c = {0.f, 0.f, 0.f, 0.f};
        c = __builtin_amdgcn_mfma_f32_16x16x32_bf16(afr[m][0], bfr[0][n], c, 0, 0, 0);
        c = __builtin_amdgcn_mfma_f32_16x16x32_bf16(afr[m][1], bfr[1][n], c, 0, 0, 0);
        acc[m][n] = c;
      }

    // acc = Mt (unnorm.); true M^T = diag(e^pm0) . acc . e^nu
    float tl = sLin[l];
    float mL = tl;
    mL = fmaxf(mL, __shfl_xor(mL, 1));  mL = fmaxf(mL, __shfl_xor(mL, 2));
    mL = fmaxf(mL, __shfl_xor(mL, 4));  mL = fmaxf(mL, __shfl_xor(mL, 8));
    mL = fmaxf(mL, __shfl_xor(mL, 16)); mL = fmaxf(mL, __shfl_xor(mL, 32));
    float wn[4];
#pragma unroll
    for (int n = 0; n < 4; ++n) wn[n] = __expf(sLin[16 * n + c4] - mL);

    float pj = pm[0][l];
    float kap = pj;
    kap = fmaxf(kap, __shfl_xor(kap, 1));  kap = fmaxf(kap, __shfl_xor(kap, 2));
    kap = fmaxf(kap, __shfl_xor(kap, 4));  kap = fmaxf(kap, __shfl_xor(kap, 8));
    kap = fmaxf(kap, __shfl_xor(kap, 16)); kap = fmaxf(kap, __shfl_xor(kap, 32));

    float tot = 0.f;
#pragma unroll
    for (int m = 0; m < 4; ++m)
#pragma unroll
      for (int r = 0; r < 4; ++r) {
        float p = acc[m][0][r] * wn[0] + acc[m][1][r] * wn[1] +
                  acc[m][2][r] * wn[2] + acc[m][3][r] * wn[3];
        p += __shfl_xor(p, 1); p += __shfl_xor(p, 2);
        p += __shfl_xor(p, 4); p += __shfl_xor(p, 8);
        if (c4 == 0) {
          int j = 16 * m + 4 * q + r;
          tot += __expf(pm[0][j] - kap) * p;
        }
      }
    tot += __shfl_xor(tot, 16);
    tot += __shfl_xor(tot, 32);
    if (l == 0) out[b] = nu + mL + kap + __logf(tot);
  }
}

extern "C" void kernel_launch(void* const* d_in, const int* in_sizes, int n_in,
                              void* d_out, int out_size, void* d_ws, size_t ws_size,
                              hipStream_t stream) {
  (void)in_sizes; (void)n_in; (void)out_size; (void)ws_size;
  const float* lf    = (const float*)d_in[0];  // [B,T,S,S] fp32
  const float* linit = (const float*)d_in[1];  // [B,S] fp32
  float* out = (float*)d_out;                  // [B] fp32

  unsigned short* wsX = (unsigned short*)d_ws;                  // 8 MB bf16
  float*          wsM = (float*)(wsX + (size_t)HMM_B * HMM_C * 4096);  // 256 KB

  hmm_phase1<<<dim3(HMM_B * HMM_C), dim3(256), 0, stream>>>(lf, wsX, wsM);
  hmm_reduce<<<dim3(HMM_B), dim3(512), 0, stream>>>(wsX, wsM, linit, out);
}